// Round 6
// baseline (550.274 us; speedup 1.0000x reference)
//
#include <hip/hip_runtime.h>
#include <hip/hip_bf16.h>

// ---------- types ----------
typedef __bf16 bf16x8 __attribute__((ext_vector_type(8)));
typedef __bf16 bf16x4 __attribute__((ext_vector_type(4)));
typedef float  f32x4  __attribute__((ext_vector_type(4)));

__device__ __forceinline__ f32x4 mfma16(bf16x8 a, bf16x8 b, f32x4 c) {
    return __builtin_amdgcn_mfma_f32_16x16x32_bf16(a, b, c, 0, 0, 0);
}
__device__ __forceinline__ float silu_f(float v) { return v / (1.f + __expf(-v)); }
__device__ __forceinline__ float softplus_fast(float v) {
    float r = __logf(1.f + __expf(v));
    return v > 15.f ? v : r;   // exp overflow guard
}

// Problem constants
#define CC 192        // d_model
#define DI 384        // d_inner
#define LL 16384      // H*W
#define HH 128
#define WW 128

// ---------- K0: weight prep (transpose + bf16 cast) ----------
// wt_in: SWIZZLED layout [12 nc][64 n][192 k] with element index ^ ((n&7)<<3)
__global__ void k0_prep(const float* __restrict__ w_in, const float* __restrict__ w_x,
                        const float* __restrict__ w_dt, const float* __restrict__ w_out,
                        __bf16* __restrict__ wt_in, __bf16* __restrict__ wt_x,
                        __bf16* __restrict__ wt_dt, __bf16* __restrict__ wt_out) {
    int tid = blockIdx.x * blockDim.x + threadIdx.x;
    int nth = gridDim.x * blockDim.x;
    for (int i = tid; i < 768 * 192; i += nth) {
        int nf = i / 192, k = i % 192;
        int nc = nf >> 6, n = nf & 63;
        int e = (n * 192 + k) ^ ((n & 7) << 3);      // bijective within 12288-elem tile
        wt_in[nc * 12288 + e] = (__bf16)w_in[k * 768 + nf];
    }
    for (int i = tid; i < 32 * 384;  i += nth) { int n = i / 384, k = i % 384; wt_x[i]  = (__bf16)w_x[k * 32 + n]; }
    for (int i = tid; i < 384 * 16;  i += nth) { int ch = i / 16, k = i % 16;  wt_dt[i] = (__bf16)w_dt[k * 384 + ch]; }
    for (int i = tid; i < 192 * 384; i += nth) { int n = i / 384, k = i % 384; wt_out[i] = (__bf16)w_out[k * 192 + n]; }
}

// ---------- K1: x_proj GEMM (R5-exact: global_load_lds DMA engine, frozen) ----------
__global__ __launch_bounds__(256, 2) void k1_proj(
        const float* __restrict__ x, const __bf16* __restrict__ wt_in,
        __bf16* __restrict__ xin, __bf16* __restrict__ zsb) {
    __shared__ __attribute__((aligned(16))) __bf16 Bs[2][12288];     // 49152 B
    __shared__ __attribute__((aligned(16))) __bf16 bounce[4][32 * 68]; // 17408 B
    const int tid = threadIdx.x;
    const int lane = tid & 63, wv = tid >> 6;
    const int lq = lane & 15, quad = lane >> 4;
    const long mbase = (long)blockIdx.x * 128;
    __bf16* bb = &bounce[wv][0];

    bf16x8 af[2][6];
#pragma unroll
    for (int mt = 0; mt < 2; mt++) {
        const float* xr = x + (mbase + wv * 32 + mt * 16 + lq) * CC;
#pragma unroll
        for (int ks = 0; ks < 6; ks++) {
            float4 v0 = *(const float4*)(xr + ks * 32 + quad * 8);
            float4 v1 = *(const float4*)(xr + ks * 32 + quad * 8 + 4);
            bf16x8 t;
            t[0] = (__bf16)v0.x; t[1] = (__bf16)v0.y; t[2] = (__bf16)v0.z; t[3] = (__bf16)v0.w;
            t[4] = (__bf16)v1.x; t[5] = (__bf16)v1.y; t[6] = (__bf16)v1.z; t[7] = (__bf16)v1.w;
            af[mt][ks] = t;
        }
    }

    auto stage = [&](int b, int nc) {
        const char* src = (const char*)(wt_in + nc * 12288);
        char* dst = (char*)&Bs[b][0];
#pragma unroll
        for (int i = 0; i < 6; i++) {
            int off = (wv * 6 + i) * 1024;
            __builtin_amdgcn_global_load_lds(
                (const __attribute__((address_space(1))) void*)(src + off + lane * 16),
                (__attribute__((address_space(3))) void*)(dst + off),
                16, 0, 0);
        }
    };

    stage(0, 0);
    __syncthreads();

    int buf = 0;
    for (int nc = 0; nc < 12; nc++) {
        if (nc < 11) stage(buf ^ 1, nc + 1);

        f32x4 A0[4], A1[4];
#pragma unroll
        for (int nt = 0; nt < 4; nt++) {
            A0[nt] = (f32x4){0.f, 0.f, 0.f, 0.f};
            A1[nt] = (f32x4){0.f, 0.f, 0.f, 0.f};
#pragma unroll
            for (int ks = 0; ks < 6; ks++) {
                const int row = nt * 16 + lq;
                const int e = (row * 192 + ks * 32 + quad * 8) ^ ((lq & 7) << 3);
                bf16x8 bf = *(const bf16x8*)(&Bs[buf][e]);
                A0[nt] = mfma16(af[0][ks], bf, A0[nt]);
                A1[nt] = mfma16(af[1][ks], bf, A1[nt]);
            }
        }
        const bool isz = (nc >= 6);
#pragma unroll
        for (int nt = 0; nt < 4; nt++) {
#pragma unroll
            for (int r = 0; r < 4; r++) {
                float v0 = A0[nt][r], v1 = A1[nt][r];
                if (isz) { v0 = silu_f(v0); v1 = silu_f(v1); }
                bb[(quad * 4 + r) * 68 + nt * 16 + lq] = (__bf16)v0;
                bb[(16 + quad * 4 + r) * 68 + nt * 16 + lq] = (__bf16)v1;
            }
        }
        __builtin_amdgcn_wave_barrier();
        __bf16* dst = isz ? zsb : xin;
        const int chb = (isz ? nc - 6 : nc) * 64;
#pragma unroll
        for (int k = 0; k < 4; k++) {
            int u = lane + k * 64;
            int row = u >> 3, c8 = u & 7;
            unsigned long long lo = *(const unsigned long long*)(&bb[row * 68 + c8 * 8]);
            unsigned long long hi = *(const unsigned long long*)(&bb[row * 68 + c8 * 8 + 4]);
            ulonglong2 val; val.x = lo; val.y = hi;
            *(ulonglong2*)(dst + (mbase + wv * 32 + row) * DI + chb + c8 * 8) = val;
        }
        __syncthreads();
        buf ^= 1;
    }
}

// ---------- K3: fused conv+ssm, 512 threads (8 waves) per 64-token block ----------
// R4 structure with the spill REMOVED: __launch_bounds__(512,2) -> VGPR cap 256,
// allocator unconstrained (R4's (512,4) forced VGPR=64 + 64 MiB scratch spill, which
// ate the halved-chain win). 2 blocks/CU x 8 waves = 4 waves/SIMD.
__global__ __launch_bounds__(512, 2) void k3_ssm(
        const __bf16* __restrict__ xin, const __bf16* __restrict__ zsb,
        const __bf16* __restrict__ wtx, const __bf16* __restrict__ wtdt,
        const __bf16* __restrict__ wtout, const float* __restrict__ wconv,
        const float* __restrict__ bconv, const float* __restrict__ bdt,
        const float* __restrict__ dskip, const float* __restrict__ gamma,
        const float* __restrict__ beta, float* __restrict__ out) {
    __shared__ __attribute__((aligned(16))) float smem0[13056];   // 52224 B: xcb bf16[64][392] / otile f32[192][68]
    __shared__ __attribute__((aligned(16))) __bf16 dts[64 * 200]; // 25600 B overlay: wcvs -> Bf/Cf -> dt
    __shared__ float bcarr[64];                                   // 256 B
    __bf16* xcb = (__bf16*)smem0;
    float* otile = smem0;

    const int tid = threadIdx.x;
    const int lane = tid & 63, wv = tid >> 6;     // wv 0..7
    const int lq = lane & 15, quad = lane >> 4;
    const int t0g = blockIdx.x * 64;

    const int te = tid >> 3, part = tid & 7;      // epilogue mapping: 8 parts x 24 ch
    const long tok = t0g + te;

    // Z-prefetch: 6 bf16x8 (24 VGPR) issued now, consumed in the epilogue phases later.
    bf16x8 zpre[6];
#pragma unroll
    for (int h = 0; h < 2; h++)
#pragma unroll
        for (int g = 0; g < 3; g++)
            zpre[h * 3 + g] = *(const bf16x8*)(zsb + tok * DI + h * 192 + part * 24 + g * 8);

    // P0a: stage conv weights into dts overlay (wcvs [9][384] + bcvs [384] = 15360 B)
    float* wcvs = (float*)dts;
    float* bcvs = wcvs + 9 * 384;
    for (int u = tid; u < 9 * 384; u += 512) { int ch = u / 9, tap = u % 9; wcvs[tap * 384 + ch] = wconv[u]; }
    for (int u = tid; u < 384; u += 512) bcvs[u] = bconv[u];
    __syncthreads();

    // P0b: depthwise 3x3 conv + bias + silu, straight from xin -> xcb tile (6 units/thr)
    const int hblk = (t0g & (LL - 1)) >> 7;   // uniform per block (64 tokens = half row)
    const int w0 = t0g & 127;                 // 0 or 64
#pragma unroll
    for (int k = 0; k < 6; k++) {
        int u = tid + k * 512;
        int t = u / 48, c8 = u % 48;
        long tk = t0g + t;
        float acc[8];
        float4 b0 = *(const float4*)(bcvs + c8 * 8);
        float4 b1 = *(const float4*)(bcvs + c8 * 8 + 4);
        acc[0] = b0.x; acc[1] = b0.y; acc[2] = b0.z; acc[3] = b0.w;
        acc[4] = b1.x; acc[5] = b1.y; acc[6] = b1.z; acc[7] = b1.w;
#pragma unroll
        for (int dy = -1; dy <= 1; dy++) {
            int h2 = hblk + dy;
            if (h2 < 0 || h2 >= HH) continue;   // block-uniform branch
#pragma unroll
            for (int dx = -1; dx <= 1; dx++) {
                int w2 = w0 + t + dx;
                if (w2 < 0 || w2 >= WW) continue;
                bf16x8 v = *(const bf16x8*)(xin + (tk + dy * WW + dx) * (long)DI + c8 * 8);
                const float* wp = &wcvs[((dy + 1) * 3 + (dx + 1)) * 384 + c8 * 8];
#pragma unroll
                for (int j = 0; j < 8; j++) acc[j] += (float)v[j] * wp[j];
            }
        }
        bf16x8 r;
#pragma unroll
        for (int j = 0; j < 8; j++) r[j] = (__bf16)silu_f(acc[j]);
        *(bf16x8*)(&xcb[t * 392 + c8 * 8]) = r;
    }
    __syncthreads();

    // P2: x_ssm = xc @ w_x. Wave split: wv&3 = token tile, wv>>2 = B(0) / C(1).
    // Output staged f32 into dts overlay: Bf/Cf [64][20] (stride 20 -> 16B-aligned rows).
    float* Bf = (float*)dts;
    float* Cf = Bf + 64 * 20;
    {
        const int wt = wv & 3, wsel = wv >> 2;
        f32x4 a4 = {0.f, 0.f, 0.f, 0.f};
#pragma unroll
        for (int ks = 0; ks < 12; ks++) {
            bf16x8 a = *(const bf16x8*)(&xcb[(wt * 16 + lq) * 392 + ks * 32 + quad * 8]);
            bf16x8 b = *(const bf16x8*)(wtx + (wsel * 16 + lq) * 384 + ks * 32 + quad * 8);
            a4 = mfma16(a, b, a4);
        }
        float* dstf = wsel ? Cf : Bf;
#pragma unroll
        for (int r = 0; r < 4; r++)
            dstf[(wt * 16 + quad * 4 + r) * 20 + lq] = a4[r];
    }
    __syncthreads();

    // bc = sum_s B*C per token (8-lane shfl tree), and aA fragments for dt MFMA
    {
        int t = tid >> 3;
        int s0 = (tid & 7) * 2;
        float p = Bf[t * 20 + s0] * Cf[t * 20 + s0] + Bf[t * 20 + s0 + 1] * Cf[t * 20 + s0 + 1];
        p += __shfl_xor(p, 1, 64);
        p += __shfl_xor(p, 2, 64);
        p += __shfl_xor(p, 4, 64);
        if ((lane & 7) == 0) bcarr[t] = p;
    }
    bf16x8 zero8;
#pragma unroll
    for (int j = 0; j < 8; j++) zero8[j] = (__bf16)0.f;
    bf16x8 aA[4];
#pragma unroll
    for (int mt = 0; mt < 4; mt++) {
        if (quad < 2) {
            const float* bp = Bf + (mt * 16 + lq) * 20 + quad * 8;
            f32x4 lo = *(const f32x4*)(bp);
            f32x4 hi = *(const f32x4*)(bp + 4);
            bf16x8 t8;
            t8[0] = (__bf16)lo[0]; t8[1] = (__bf16)lo[1]; t8[2] = (__bf16)lo[2]; t8[3] = (__bf16)lo[3];
            t8[4] = (__bf16)hi[0]; t8[5] = (__bf16)hi[1]; t8[6] = (__bf16)hi[2]; t8[7] = (__bf16)hi[3];
            aA[mt] = t8;
        } else {
            aA[mt] = zero8;
        }
    }
    __syncthreads();   // bcarr visible; Bf/Cf reads done before dt scatter overwrites

    float s1 = 0.f, s2 = 0.f;

#pragma unroll
    for (int h = 0; h < 2; h++) {
        // P3a: dt MFMA. 12 n-tiles: tile = wv + 8*j (waves 0-3 get 2, waves 4-7 get 1).
        f32x4 dacc[2][4];
        float bdtv[2];
#pragma unroll
        for (int j = 0; j < 2; j++) {
            const int tile = wv + 8 * j;
            if (tile < 12) {
                int chg = h * 192 + tile * 16 + lq;
                bf16x8 bf = (quad < 2) ? *(const bf16x8*)(wtdt + (long)chg * 16 + quad * 8) : zero8;
                bdtv[j] = bdt[chg];
#pragma unroll
                for (int mt = 0; mt < 4; mt++) {
                    f32x4 z4 = {0.f, 0.f, 0.f, 0.f};
                    dacc[j][mt] = mfma16(aA[mt], bf, z4);
                }
            }
        }
        // scatter dt(+b_dt) to LDS (stride 200)
#pragma unroll
        for (int j = 0; j < 2; j++) {
            const int tile = wv + 8 * j;
            if (tile < 12) {
#pragma unroll
                for (int mt = 0; mt < 4; mt++)
#pragma unroll
                    for (int r = 0; r < 4; r++)
                        dts[(mt * 16 + quad * 4 + r) * 200 + tile * 16 + lq] =
                            (__bf16)(dacc[j][mt][r] + bdtv[j]);
            }
        }
        __syncthreads();

        // epilogue: y = (softplus(dt)*bc + xc*dskip) * z ; accumulate LN stats (3 groups)
#pragma unroll
        for (int g = 0; g < 3; g++) {
            const int chl = part * 24 + g * 8;
            const int chg = h * 192 + chl;
            bf16x8 d8 = *(const bf16x8*)(&dts[te * 200 + chl]);
            bf16x8 xc8 = *(const bf16x8*)(&xcb[te * 392 + chg]);
            bf16x8 z8 = zpre[h * 3 + g];
            float4 d0 = *(const float4*)(dskip + chg);
            float4 d1 = *(const float4*)(dskip + chg + 4);
            float ds[8] = {d0.x, d0.y, d0.z, d0.w, d1.x, d1.y, d1.z, d1.w};
            const float bcv = bcarr[te];
#pragma unroll
            for (int j = 0; j < 8; j++) {
                float dtv = softplus_fast((float)d8[j]);
                float yv = (dtv * bcv + (float)xc8[j] * ds[j]) * (float)z8[j];
                s1 += yv; s2 += yv * yv;
                xc8[j] = (__bf16)yv;
            }
            *(bf16x8*)(&xcb[te * 392 + chg]) = xc8;
        }
        __syncthreads();  // dts reads done before next half's scatter
    }

    // LN (thread owns 6 channel-groups; stats reduce over 8 parts via shfl)
    {
        s1 += __shfl_xor(s1, 1, 64); s2 += __shfl_xor(s2, 1, 64);
        s1 += __shfl_xor(s1, 2, 64); s2 += __shfl_xor(s2, 2, 64);
        s1 += __shfl_xor(s1, 4, 64); s2 += __shfl_xor(s2, 4, 64);
        float mu = s1 * (1.f / 384.f);
        float var = s2 * (1.f / 384.f) - mu * mu;
        float rstd = rsqrtf(var + 1e-5f);
#pragma unroll
        for (int gg = 0; gg < 6; gg++) {
            const int h2 = gg / 3, g3 = gg % 3;
            const int ch = h2 * 192 + part * 24 + g3 * 8;
            bf16x8 v = *(const bf16x8*)(&xcb[te * 392 + ch]);
            float4 g0 = *(const float4*)(gamma + ch);
            float4 g1 = *(const float4*)(gamma + ch + 4);
            float4 be0 = *(const float4*)(beta + ch);
            float4 be1 = *(const float4*)(beta + ch + 4);
            float gm[8] = {g0.x, g0.y, g0.z, g0.w, g1.x, g1.y, g1.z, g1.w};
            float bt[8] = {be0.x, be0.y, be0.z, be0.w, be1.x, be1.y, be1.z, be1.w};
#pragma unroll
            for (int j = 0; j < 8; j++) v[j] = (__bf16)(((float)v[j] - mu) * rstd * gm[j] + bt[j]);
            *(bf16x8*)(&xcb[te * 392 + ch]) = v;
        }
    }
    __syncthreads();

    // P5: out GEMM y[64,384] @ wt_out^T -> [64,192]. wv&3 -> 3 n-tiles, wv>>2 -> m-half.
    {
        const int mh = wv >> 2, nb = (wv & 3) * 3;
        f32x4 acc[3][2];
#pragma unroll
        for (int j = 0; j < 3; j++)
#pragma unroll
            for (int m2 = 0; m2 < 2; m2++) acc[j][m2] = (f32x4){0.f, 0.f, 0.f, 0.f};
#pragma unroll
        for (int ks = 0; ks < 12; ks++) {
            bf16x8 bfr[3];
#pragma unroll
            for (int j = 0; j < 3; j++) {
                int c = (nb + j) * 16 + lq;
                bfr[j] = *(const bf16x8*)(wtout + (long)c * 384 + ks * 32 + quad * 8);
            }
#pragma unroll
            for (int m2 = 0; m2 < 2; m2++) {
                bf16x8 afr = *(const bf16x8*)(&xcb[((mh * 2 + m2) * 16 + lq) * 392 + ks * 32 + quad * 8]);
#pragma unroll
                for (int j = 0; j < 3; j++) acc[j][m2] = mfma16(afr, bfr[j], acc[j][m2]);
            }
        }
        __syncthreads();  // all y-reads done; otile overwrites xcb region
#pragma unroll
        for (int j = 0; j < 3; j++) {
            int c = (nb + j) * 16 + lq;
#pragma unroll
            for (int m2 = 0; m2 < 2; m2++)
#pragma unroll
                for (int r = 0; r < 4; r++)
                    otile[c * 68 + (mh * 2 + m2) * 16 + quad * 4 + r] = acc[j][m2][r];
        }
    }
    __syncthreads();

    // P6: store out[b][c][l]: 256 B contiguous per channel (6 units/thr)
    {
        const int bimg = t0g >> 14;
        const int l0 = t0g & (LL - 1);
#pragma unroll
        for (int k = 0; k < 6; k++) {
            int u = tid + k * 512;       // 3072 units = 192 ch x 16 float4
            int c = u >> 4, j = u & 15;
            float4 v = *(const float4*)(&otile[c * 68 + j * 4]);
            *(float4*)(out + ((long)(bimg * CC + c)) * LL + l0 + j * 4) = v;
        }
    }
}

// ---------- launch ----------
extern "C" void kernel_launch(void* const* d_in, const int* in_sizes, int n_in,
                              void* d_out, int out_size, void* d_ws, size_t ws_size,
                              hipStream_t stream) {
    (void)in_sizes; (void)n_in; (void)out_size; (void)ws_size;
    const float* x      = (const float*)d_in[0];
    const float* w_in   = (const float*)d_in[1];
    const float* w_conv = (const float*)d_in[2];
    const float* b_conv = (const float*)d_in[3];
    const float* w_x    = (const float*)d_in[4];
    const float* w_dt   = (const float*)d_in[5];
    const float* b_dt   = (const float*)d_in[6];
    const float* D_skip = (const float*)d_in[7];
    const float* w_out  = (const float*)d_in[8];
    const float* gamma  = (const float*)d_in[9];
    const float* beta   = (const float*)d_in[10];
    float* out = (float*)d_out;

    char* ws = (char*)d_ws;
    __bf16* wt_in  = (__bf16*)(ws);                       // 294912 B (swizzled layout)
    __bf16* wt_x   = (__bf16*)(ws + 294912);              // 24576 B
    __bf16* wt_dt  = (__bf16*)(ws + 319488);              // 12288 B
    __bf16* wt_out = (__bf16*)(ws + 331776);              // 147456 B
    __bf16* xin    = (__bf16*)(ws + 479232);              // 100663296 B
    __bf16* zsb    = (__bf16*)(ws + 479232 + 100663296);  // 100663296 B

    k0_prep<<<96, 256, 0, stream>>>(w_in, w_x, w_dt, w_out, wt_in, wt_x, wt_dt, wt_out);
    k1_proj<<<1024, 256, 0, stream>>>(x, wt_in, xin, zsb);
    k3_ssm<<<2048, 512, 0, stream>>>(xin, zsb, wt_x, wt_dt, wt_out, w_conv, b_conv,
                                     b_dt, D_skip, gamma, beta, out);
}

// Round 7
// 498.800 us; speedup vs baseline: 1.1032x; 1.1032x over previous
//
#include <hip/hip_runtime.h>
#include <hip/hip_bf16.h>

// ---------- types ----------
typedef __bf16 bf16x8 __attribute__((ext_vector_type(8)));
typedef __bf16 bf16x4 __attribute__((ext_vector_type(4)));
typedef float  f32x4  __attribute__((ext_vector_type(4)));

__device__ __forceinline__ f32x4 mfma16(bf16x8 a, bf16x8 b, f32x4 c) {
    return __builtin_amdgcn_mfma_f32_16x16x32_bf16(a, b, c, 0, 0, 0);
}
__device__ __forceinline__ float silu_f(float v) { return v / (1.f + __expf(-v)); }
__device__ __forceinline__ float softplus_fast(float v) {
    float r = __logf(1.f + __expf(v));
    return v > 15.f ? v : r;   // exp overflow guard
}

// Problem constants
#define CC 192        // d_model
#define DI 384        // d_inner
#define LL 16384      // H*W
#define HH 128
#define WW 128
#define LTOT 131072L  // total tokens (8 images x 16384)

// xin/zsb live in CHUNK-MAJOR layout: [chunk = ch/64][token][64 ch].
// Rationale: k1 produces 64 channels per nc; storing them [token][384ch] makes
// 128-B segments at 768-B stride -> 2x HBM write amplification (measured: WRITE_SIZE
// 192 MiB for 96 MiB logical). Chunk-major makes k1's stores perfectly contiguous.

// ---------- K0: weight prep (transpose + bf16 cast) ----------
// wt_in: SWIZZLED layout [12 nc][64 n][192 k] with element index ^ ((n&7)<<3)
__global__ void k0_prep(const float* __restrict__ w_in, const float* __restrict__ w_x,
                        const float* __restrict__ w_dt, const float* __restrict__ w_out,
                        __bf16* __restrict__ wt_in, __bf16* __restrict__ wt_x,
                        __bf16* __restrict__ wt_dt, __bf16* __restrict__ wt_out) {
    int tid = blockIdx.x * blockDim.x + threadIdx.x;
    int nth = gridDim.x * blockDim.x;
    for (int i = tid; i < 768 * 192; i += nth) {
        int nf = i / 192, k = i % 192;
        int nc = nf >> 6, n = nf & 63;
        int e = (n * 192 + k) ^ ((n & 7) << 3);      // bijective within 12288-elem tile
        wt_in[nc * 12288 + e] = (__bf16)w_in[k * 768 + nf];
    }
    for (int i = tid; i < 32 * 384;  i += nth) { int n = i / 384, k = i % 384; wt_x[i]  = (__bf16)w_x[k * 32 + n]; }
    for (int i = tid; i < 384 * 16;  i += nth) { int ch = i / 16, k = i % 16;  wt_dt[i] = (__bf16)w_dt[k * 384 + ch]; }
    for (int i = tid; i < 192 * 384; i += nth) { int n = i / 384, k = i % 384; wt_out[i] = (__bf16)w_out[k * 192 + n]; }
}

// ---------- K1: x_proj GEMM (R5 DMA engine + chunk-major contiguous stores) ----------
__global__ __launch_bounds__(256, 2) void k1_proj(
        const float* __restrict__ x, const __bf16* __restrict__ wt_in,
        __bf16* __restrict__ xin, __bf16* __restrict__ zsb) {
    __shared__ __attribute__((aligned(16))) __bf16 Bs[2][12288];     // 49152 B
    __shared__ __attribute__((aligned(16))) __bf16 bounce[4][32 * 68]; // 17408 B
    const int tid = threadIdx.x;
    const int lane = tid & 63, wv = tid >> 6;
    const int lq = lane & 15, quad = lane >> 4;
    const long mbase = (long)blockIdx.x * 128;
    __bf16* bb = &bounce[wv][0];

    bf16x8 af[2][6];
#pragma unroll
    for (int mt = 0; mt < 2; mt++) {
        const float* xr = x + (mbase + wv * 32 + mt * 16 + lq) * CC;
#pragma unroll
        for (int ks = 0; ks < 6; ks++) {
            float4 v0 = *(const float4*)(xr + ks * 32 + quad * 8);
            float4 v1 = *(const float4*)(xr + ks * 32 + quad * 8 + 4);
            bf16x8 t;
            t[0] = (__bf16)v0.x; t[1] = (__bf16)v0.y; t[2] = (__bf16)v0.z; t[3] = (__bf16)v0.w;
            t[4] = (__bf16)v1.x; t[5] = (__bf16)v1.y; t[6] = (__bf16)v1.z; t[7] = (__bf16)v1.w;
            af[mt][ks] = t;
        }
    }

    auto stage = [&](int b, int nc) {
        const char* src = (const char*)(wt_in + nc * 12288);
        char* dst = (char*)&Bs[b][0];
#pragma unroll
        for (int i = 0; i < 6; i++) {
            int off = (wv * 6 + i) * 1024;
            __builtin_amdgcn_global_load_lds(
                (const __attribute__((address_space(1))) void*)(src + off + lane * 16),
                (__attribute__((address_space(3))) void*)(dst + off),
                16, 0, 0);
        }
    };

    stage(0, 0);
    __syncthreads();

    int buf = 0;
    for (int nc = 0; nc < 12; nc++) {
        if (nc < 11) stage(buf ^ 1, nc + 1);

        f32x4 A0[4], A1[4];
#pragma unroll
        for (int nt = 0; nt < 4; nt++) {
            A0[nt] = (f32x4){0.f, 0.f, 0.f, 0.f};
            A1[nt] = (f32x4){0.f, 0.f, 0.f, 0.f};
#pragma unroll
            for (int ks = 0; ks < 6; ks++) {
                const int row = nt * 16 + lq;
                const int e = (row * 192 + ks * 32 + quad * 8) ^ ((lq & 7) << 3);
                bf16x8 bf = *(const bf16x8*)(&Bs[buf][e]);
                A0[nt] = mfma16(af[0][ks], bf, A0[nt]);
                A1[nt] = mfma16(af[1][ks], bf, A1[nt]);
            }
        }
        const bool isz = (nc >= 6);
#pragma unroll
        for (int nt = 0; nt < 4; nt++) {
#pragma unroll
            for (int r = 0; r < 4; r++) {
                float v0 = A0[nt][r], v1 = A1[nt][r];
                if (isz) { v0 = silu_f(v0); v1 = silu_f(v1); }
                bb[(quad * 4 + r) * 68 + nt * 16 + lq] = (__bf16)v0;
                bb[(16 + quad * 4 + r) * 68 + nt * 16 + lq] = (__bf16)v1;
            }
        }
        __builtin_amdgcn_wave_barrier();
        // chunk-major store: ((chunk*LTOT) + token)*64 + ch -> per instruction the
        // 64 lanes cover 8 consecutive token rows x 128 B = 1024 B CONTIGUOUS.
        __bf16* dst = isz ? zsb : xin;
        const long chunk = isz ? nc - 6 : nc;
#pragma unroll
        for (int k = 0; k < 4; k++) {
            int u = lane + k * 64;
            int row = u >> 3, c8 = u & 7;
            unsigned long long lo = *(const unsigned long long*)(&bb[row * 68 + c8 * 8]);
            unsigned long long hi = *(const unsigned long long*)(&bb[row * 68 + c8 * 8 + 4]);
            ulonglong2 val; val.x = lo; val.y = hi;
            *(ulonglong2*)(dst + (chunk * LTOT + mbase + wv * 32 + row) * 64 + c8 * 8) = val;
        }
        __syncthreads();
        buf ^= 1;
    }
}

// ---------- K3: fused conv+ssm (R3-exact structure, chunk-major xin/zsb reads) ----------
// 64 tokens/block; grid 2048; 256 thr. LDS 81408 B -> 2 blocks/CU.
__global__ __launch_bounds__(256, 2) void k3_ssm(
        const __bf16* __restrict__ xin, const __bf16* __restrict__ zsb,
        const __bf16* __restrict__ wtx, const __bf16* __restrict__ wtdt,
        const __bf16* __restrict__ wtout, const float* __restrict__ wconv,
        const float* __restrict__ bconv, const float* __restrict__ bdt,
        const float* __restrict__ dskip, const float* __restrict__ gamma,
        const float* __restrict__ beta, float* __restrict__ out) {
    __shared__ __attribute__((aligned(16))) float smem0[13056];   // 52224 B: xcb bf16[64][392] / otile f32[192][68]
    __shared__ __attribute__((aligned(16))) __bf16 dts[64 * 200]; // 25600 B: dt half-tile; P0: conv weights
    __shared__ __attribute__((aligned(16))) __bf16 bss[64 * 24];  // 3072 B
    __shared__ float bcarr[64];                                   // 256 B
    __bf16* xcb = (__bf16*)smem0;
    float* otile = smem0;

    const int tid = threadIdx.x;
    const int lane = tid & 63, wv = tid >> 6;
    const int lq = lane & 15, quad = lane >> 4;
    const int t0g = blockIdx.x * 64;

    const int te = tid >> 2, part = tid & 3;     // epilogue mapping
    const long tok = t0g + te;

    // Z-prefetch from chunk-major zsb (48 VGPR), consumed in the epilogue later.
    bf16x8 zpre[12];
#pragma unroll
    for (int h = 0; h < 2; h++)
#pragma unroll
        for (int g = 0; g < 6; g++) {
            const int chg = h * 192 + part * 48 + g * 8;
            zpre[h * 6 + g] = *(const bf16x8*)(zsb + ((long)(chg >> 6) * LTOT + tok) * 64 + (chg & 63));
        }

    // P0a: stage conv weights into dts region (wcvs [9][384] + bcvs [384] = 15360 B)
    float* wcvs = (float*)dts;
    float* bcvs = wcvs + 9 * 384;
    for (int u = tid; u < 9 * 384; u += 256) { int ch = u / 9, tap = u % 9; wcvs[tap * 384 + ch] = wconv[u]; }
    for (int u = tid; u < 384; u += 256) bcvs[u] = bconv[u];
    __syncthreads();

    // P0b: depthwise 3x3 conv + bias + silu, straight from chunk-major xin -> xcb tile
    const int hblk = (t0g & (LL - 1)) >> 7;   // uniform per block (64 tokens = half row)
    const int w0 = t0g & 127;                 // 0 or 64
#pragma unroll
    for (int k = 0; k < 12; k++) {
        int u = tid + k * 256;
        int t = u / 48, c8 = u % 48;
        long tk = t0g + t;
        const long cbase = (long)(c8 >> 3) * LTOT;   // chunk base for this 8-ch group
        const int coff = (c8 & 7) * 8;
        float acc[8];
        float4 b0 = *(const float4*)(bcvs + c8 * 8);
        float4 b1 = *(const float4*)(bcvs + c8 * 8 + 4);
        acc[0] = b0.x; acc[1] = b0.y; acc[2] = b0.z; acc[3] = b0.w;
        acc[4] = b1.x; acc[5] = b1.y; acc[6] = b1.z; acc[7] = b1.w;
#pragma unroll
        for (int dy = -1; dy <= 1; dy++) {
            int h2 = hblk + dy;
            if (h2 < 0 || h2 >= HH) continue;   // block-uniform branch
#pragma unroll
            for (int dx = -1; dx <= 1; dx++) {
                int w2 = w0 + t + dx;
                if (w2 < 0 || w2 >= WW) continue;
                bf16x8 v = *(const bf16x8*)(xin + (cbase + tk + dy * WW + dx) * 64 + coff);
                const float* wp = &wcvs[((dy + 1) * 3 + (dx + 1)) * 384 + c8 * 8];
#pragma unroll
                for (int j = 0; j < 8; j++) acc[j] += (float)v[j] * wp[j];
            }
        }
        bf16x8 r;
#pragma unroll
        for (int j = 0; j < 8; j++) r[j] = (__bf16)silu_f(acc[j]);
        *(bf16x8*)(&xcb[t * 392 + c8 * 8]) = r;
    }
    __syncthreads();

    // P2: x_ssm = xc @ w_x (K=384, N=32); bc = sum_s B*C; stash B_ssm bf16
    {
        f32x4 aB = {0.f, 0.f, 0.f, 0.f}, aC = {0.f, 0.f, 0.f, 0.f};
#pragma unroll
        for (int ks = 0; ks < 12; ks++) {
            bf16x8 a = *(const bf16x8*)(&xcb[(wv * 16 + lq) * 392 + ks * 32 + quad * 8]);
            bf16x8 b0 = *(const bf16x8*)(wtx + lq * 384 + ks * 32 + quad * 8);
            bf16x8 b1 = *(const bf16x8*)(wtx + (16 + lq) * 384 + ks * 32 + quad * 8);
            aB = mfma16(a, b0, aB);
            aC = mfma16(a, b1, aC);
        }
        float p0 = aB[0] * aC[0], p1 = aB[1] * aC[1], p2 = aB[2] * aC[2], p3 = aB[3] * aC[3];
#pragma unroll
        for (int m = 1; m < 16; m <<= 1) {
            p0 += __shfl_xor(p0, m, 64);
            p1 += __shfl_xor(p1, m, 64);
            p2 += __shfl_xor(p2, m, 64);
            p3 += __shfl_xor(p3, m, 64);
        }
        int trow = wv * 16 + quad * 4;
        if (lq == 0) { bcarr[trow] = p0; bcarr[trow + 1] = p1; bcarr[trow + 2] = p2; bcarr[trow + 3] = p3; }
        bss[(trow + 0) * 24 + lq] = (__bf16)aB[0];
        bss[(trow + 1) * 24 + lq] = (__bf16)aB[1];
        bss[(trow + 2) * 24 + lq] = (__bf16)aB[2];
        bss[(trow + 3) * 24 + lq] = (__bf16)aB[3];
    }
    __syncthreads();

    bf16x8 zero8;
#pragma unroll
    for (int j = 0; j < 8; j++) zero8[j] = (__bf16)0.f;

    // A-fragments for dt MFMA (K=16 lives in quads 0,1; quads 2,3 feed zeros)
    bf16x8 aA[4];
#pragma unroll
    for (int mt = 0; mt < 4; mt++)
        aA[mt] = (quad < 2) ? *(const bf16x8*)(&bss[(mt * 16 + lq) * 24 + quad * 8]) : zero8;

    float s1 = 0.f, s2 = 0.f;

#pragma unroll
    for (int h = 0; h < 2; h++) {
        // P3a: dt MFMA for channels h*192 .. h*192+191 (3 n-tiles per wave)
        f32x4 dacc[3][4];
        float bdtv[3];
#pragma unroll
        for (int j = 0; j < 3; j++) {
            int chg = h * 192 + (wv * 3 + j) * 16 + lq;
            bf16x8 bf = (quad < 2) ? *(const bf16x8*)(wtdt + (long)chg * 16 + quad * 8) : zero8;
            bdtv[j] = bdt[chg];
#pragma unroll
            for (int mt = 0; mt < 4; mt++) {
                f32x4 z4 = {0.f, 0.f, 0.f, 0.f};
                dacc[j][mt] = mfma16(aA[mt], bf, z4);
            }
        }
        // scatter dt(+b_dt) to LDS (stride 200 -> conflict-free)
#pragma unroll
        for (int j = 0; j < 3; j++)
#pragma unroll
            for (int mt = 0; mt < 4; mt++)
#pragma unroll
                for (int r = 0; r < 4; r++)
                    dts[(mt * 16 + quad * 4 + r) * 200 + (wv * 3 + j) * 16 + lq] =
                        (__bf16)(dacc[j][mt][r] + bdtv[j]);
        __syncthreads();

        // epilogue: y = (softplus(dt)*bc + xc*dskip) * z ; accumulate LN stats
#pragma unroll
        for (int g = 0; g < 6; g++) {
            const int chl = part * 48 + g * 8;
            const int chg = h * 192 + chl;
            bf16x8 d8 = *(const bf16x8*)(&dts[te * 200 + chl]);
            bf16x8 xc8 = *(const bf16x8*)(&xcb[te * 392 + chg]);
            bf16x8 z8 = zpre[h * 6 + g];
            float4 d0 = *(const float4*)(dskip + chg);
            float4 d1 = *(const float4*)(dskip + chg + 4);
            float ds[8] = {d0.x, d0.y, d0.z, d0.w, d1.x, d1.y, d1.z, d1.w};
            const float bcv = bcarr[te];
#pragma unroll
            for (int j = 0; j < 8; j++) {
                float dtv = softplus_fast((float)d8[j]);
                float yv = (dtv * bcv + (float)xc8[j] * ds[j]) * (float)z8[j];
                s1 += yv; s2 += yv * yv;
                xc8[j] = (__bf16)yv;
            }
            *(bf16x8*)(&xcb[te * 392 + chg]) = xc8;
        }
        __syncthreads();  // dts reads done before next half's scatter
    }

    // LN (thread owns its 12 channel-groups across both halves)
    {
        s1 += __shfl_xor(s1, 1, 64); s2 += __shfl_xor(s2, 1, 64);
        s1 += __shfl_xor(s1, 2, 64); s2 += __shfl_xor(s2, 2, 64);
        float mu = s1 * (1.f / 384.f);
        float var = s2 * (1.f / 384.f) - mu * mu;
        float rstd = rsqrtf(var + 1e-5f);
#pragma unroll
        for (int gg = 0; gg < 12; gg++) {
            const int h2 = gg / 6, g6 = gg % 6;
            const int ch = h2 * 192 + part * 48 + g6 * 8;
            bf16x8 v = *(const bf16x8*)(&xcb[te * 392 + ch]);
            float4 g0 = *(const float4*)(gamma + ch);
            float4 g1 = *(const float4*)(gamma + ch + 4);
            float4 be0 = *(const float4*)(beta + ch);
            float4 be1 = *(const float4*)(beta + ch + 4);
            float gm[8] = {g0.x, g0.y, g0.z, g0.w, g1.x, g1.y, g1.z, g1.w};
            float bt[8] = {be0.x, be0.y, be0.z, be0.w, be1.x, be1.y, be1.z, be1.w};
#pragma unroll
            for (int j = 0; j < 8; j++) v[j] = (__bf16)(((float)v[j] - mu) * rstd * gm[j] + bt[j]);
            *(bf16x8*)(&xcb[te * 392 + ch]) = v;
        }
    }
    __syncthreads();

    // P5: out GEMM y[64,384] @ wt_out^T -> [64,192]; waves split N (3 n-tiles each)
    {
        f32x4 acc[3][4];
#pragma unroll
        for (int j = 0; j < 3; j++)
#pragma unroll
            for (int mt = 0; mt < 4; mt++) acc[j][mt] = (f32x4){0.f, 0.f, 0.f, 0.f};
#pragma unroll
        for (int ks = 0; ks < 12; ks++) {
            bf16x8 bfr[3];
#pragma unroll
            for (int j = 0; j < 3; j++) {
                int c = (wv * 3 + j) * 16 + lq;
                bfr[j] = *(const bf16x8*)(wtout + (long)c * 384 + ks * 32 + quad * 8);
            }
#pragma unroll
            for (int mt = 0; mt < 4; mt++) {
                bf16x8 afr = *(const bf16x8*)(&xcb[(mt * 16 + lq) * 392 + ks * 32 + quad * 8]);
#pragma unroll
                for (int j = 0; j < 3; j++) acc[j][mt] = mfma16(afr, bfr[j], acc[j][mt]);
            }
        }
        __syncthreads();  // all y-reads done; otile overwrites xcb region
#pragma unroll
        for (int j = 0; j < 3; j++) {
            int c = (wv * 3 + j) * 16 + lq;
#pragma unroll
            for (int mt = 0; mt < 4; mt++)
#pragma unroll
                for (int r = 0; r < 4; r++)
                    otile[c * 68 + mt * 16 + quad * 4 + r] = acc[j][mt][r];
        }
    }
    __syncthreads();

    // P6: store out[b][c][l]: 256 B contiguous per channel
    {
        const int bimg = t0g >> 14;
        const int l0 = t0g & (LL - 1);
#pragma unroll
        for (int k = 0; k < 12; k++) {
            int u = tid + k * 256;       // 3072 units = 192 ch x 16 float4
            int c = u >> 4, j = u & 15;
            float4 v = *(const float4*)(&otile[c * 68 + j * 4]);
            *(float4*)(out + ((long)(bimg * CC + c)) * LL + l0 + j * 4) = v;
        }
    }
}

// ---------- launch ----------
extern "C" void kernel_launch(void* const* d_in, const int* in_sizes, int n_in,
                              void* d_out, int out_size, void* d_ws, size_t ws_size,
                              hipStream_t stream) {
    (void)in_sizes; (void)n_in; (void)out_size; (void)ws_size;
    const float* x      = (const float*)d_in[0];
    const float* w_in   = (const float*)d_in[1];
    const float* w_conv = (const float*)d_in[2];
    const float* b_conv = (const float*)d_in[3];
    const float* w_x    = (const float*)d_in[4];
    const float* w_dt   = (const float*)d_in[5];
    const float* b_dt   = (const float*)d_in[6];
    const float* D_skip = (const float*)d_in[7];
    const float* w_out  = (const float*)d_in[8];
    const float* gamma  = (const float*)d_in[9];
    const float* beta   = (const float*)d_in[10];
    float* out = (float*)d_out;

    char* ws = (char*)d_ws;
    __bf16* wt_in  = (__bf16*)(ws);                       // 294912 B (swizzled layout)
    __bf16* wt_x   = (__bf16*)(ws + 294912);              // 24576 B
    __bf16* wt_dt  = (__bf16*)(ws + 319488);              // 12288 B
    __bf16* wt_out = (__bf16*)(ws + 331776);              // 147456 B
    __bf16* xin    = (__bf16*)(ws + 479232);              // 100663296 B (chunk-major)
    __bf16* zsb    = (__bf16*)(ws + 479232 + 100663296);  // 100663296 B (chunk-major)

    k0_prep<<<96, 256, 0, stream>>>(w_in, w_x, w_dt, w_out, wt_in, wt_x, wt_dt, wt_out);
    k1_proj<<<1024, 256, 0, stream>>>(x, wt_in, xin, zsb);
    k3_ssm<<<2048, 256, 0, stream>>>(xin, zsb, wt_x, wt_dt, wt_out, w_conv, b_conv,
                                     b_dt, D_skip, gamma, beta, out);
}

// Round 8
// 468.282 us; speedup vs baseline: 1.1751x; 1.0652x over previous
//
#include <hip/hip_runtime.h>
#include <hip/hip_bf16.h>

// ---------- types ----------
typedef __bf16 bf16x8 __attribute__((ext_vector_type(8)));
typedef __bf16 bf16x4 __attribute__((ext_vector_type(4)));
typedef float  f32x4  __attribute__((ext_vector_type(4)));

__device__ __forceinline__ f32x4 mfma16(bf16x8 a, bf16x8 b, f32x4 c) {
    return __builtin_amdgcn_mfma_f32_16x16x32_bf16(a, b, c, 0, 0, 0);
}
__device__ __forceinline__ float silu_f(float v) { return v / (1.f + __expf(-v)); }
__device__ __forceinline__ float softplus_fast(float v) {
    float r = __logf(1.f + __expf(v));
    return v > 15.f ? v : r;   // exp overflow guard
}

// Problem constants
#define CC 192        // d_model
#define DI 384        // d_inner
#define LL 16384      // H*W
#define HH 128
#define WW 128
#define LTOT 131072L  // total tokens (8 images x 16384)

// xin/zsb live in CHUNK-MAJOR layout: [chunk = ch/64][token][64 ch].

// ---------- K0: weight prep (transpose + bf16 cast) ----------
// wt_in: SWIZZLED layout [12 nc][64 n][192 k] with element index ^ ((n&7)<<3)
__global__ void k0_prep(const float* __restrict__ w_in, const float* __restrict__ w_x,
                        const float* __restrict__ w_dt, const float* __restrict__ w_out,
                        __bf16* __restrict__ wt_in, __bf16* __restrict__ wt_x,
                        __bf16* __restrict__ wt_dt, __bf16* __restrict__ wt_out) {
    int tid = blockIdx.x * blockDim.x + threadIdx.x;
    int nth = gridDim.x * blockDim.x;
    for (int i = tid; i < 768 * 192; i += nth) {
        int nf = i / 192, k = i % 192;
        int nc = nf >> 6, n = nf & 63;
        int e = (n * 192 + k) ^ ((n & 7) << 3);      // bijective within 12288-elem tile
        wt_in[nc * 12288 + e] = (__bf16)w_in[k * 768 + nf];
    }
    for (int i = tid; i < 32 * 384;  i += nth) { int n = i / 384, k = i % 384; wt_x[i]  = (__bf16)w_x[k * 32 + n]; }
    for (int i = tid; i < 384 * 16;  i += nth) { int ch = i / 16, k = i % 16;  wt_dt[i] = (__bf16)w_dt[k * 384 + ch]; }
    for (int i = tid; i < 192 * 384; i += nth) { int n = i / 384, k = i % 384; wt_out[i] = (__bf16)w_out[k * 192 + n]; }
}

// ---------- K1: x_proj GEMM (R5/R7 DMA engine + chunk-major stores; FROZEN) ----------
__global__ __launch_bounds__(256, 2) void k1_proj(
        const float* __restrict__ x, const __bf16* __restrict__ wt_in,
        __bf16* __restrict__ xin, __bf16* __restrict__ zsb) {
    __shared__ __attribute__((aligned(16))) __bf16 Bs[2][12288];     // 49152 B
    __shared__ __attribute__((aligned(16))) __bf16 bounce[4][32 * 68]; // 17408 B
    const int tid = threadIdx.x;
    const int lane = tid & 63, wv = tid >> 6;
    const int lq = lane & 15, quad = lane >> 4;
    const long mbase = (long)blockIdx.x * 128;
    __bf16* bb = &bounce[wv][0];

    bf16x8 af[2][6];
#pragma unroll
    for (int mt = 0; mt < 2; mt++) {
        const float* xr = x + (mbase + wv * 32 + mt * 16 + lq) * CC;
#pragma unroll
        for (int ks = 0; ks < 6; ks++) {
            float4 v0 = *(const float4*)(xr + ks * 32 + quad * 8);
            float4 v1 = *(const float4*)(xr + ks * 32 + quad * 8 + 4);
            bf16x8 t;
            t[0] = (__bf16)v0.x; t[1] = (__bf16)v0.y; t[2] = (__bf16)v0.z; t[3] = (__bf16)v0.w;
            t[4] = (__bf16)v1.x; t[5] = (__bf16)v1.y; t[6] = (__bf16)v1.z; t[7] = (__bf16)v1.w;
            af[mt][ks] = t;
        }
    }

    auto stage = [&](int b, int nc) {
        const char* src = (const char*)(wt_in + nc * 12288);
        char* dst = (char*)&Bs[b][0];
#pragma unroll
        for (int i = 0; i < 6; i++) {
            int off = (wv * 6 + i) * 1024;
            __builtin_amdgcn_global_load_lds(
                (const __attribute__((address_space(1))) void*)(src + off + lane * 16),
                (__attribute__((address_space(3))) void*)(dst + off),
                16, 0, 0);
        }
    };

    stage(0, 0);
    __syncthreads();

    int buf = 0;
    for (int nc = 0; nc < 12; nc++) {
        if (nc < 11) stage(buf ^ 1, nc + 1);

        f32x4 A0[4], A1[4];
#pragma unroll
        for (int nt = 0; nt < 4; nt++) {
            A0[nt] = (f32x4){0.f, 0.f, 0.f, 0.f};
            A1[nt] = (f32x4){0.f, 0.f, 0.f, 0.f};
#pragma unroll
            for (int ks = 0; ks < 6; ks++) {
                const int row = nt * 16 + lq;
                const int e = (row * 192 + ks * 32 + quad * 8) ^ ((lq & 7) << 3);
                bf16x8 bf = *(const bf16x8*)(&Bs[buf][e]);
                A0[nt] = mfma16(af[0][ks], bf, A0[nt]);
                A1[nt] = mfma16(af[1][ks], bf, A1[nt]);
            }
        }
        const bool isz = (nc >= 6);
#pragma unroll
        for (int nt = 0; nt < 4; nt++) {
#pragma unroll
            for (int r = 0; r < 4; r++) {
                float v0 = A0[nt][r], v1 = A1[nt][r];
                if (isz) { v0 = silu_f(v0); v1 = silu_f(v1); }
                bb[(quad * 4 + r) * 68 + nt * 16 + lq] = (__bf16)v0;
                bb[(16 + quad * 4 + r) * 68 + nt * 16 + lq] = (__bf16)v1;
            }
        }
        __builtin_amdgcn_wave_barrier();
        __bf16* dst = isz ? zsb : xin;
        const long chunk = isz ? nc - 6 : nc;
#pragma unroll
        for (int k = 0; k < 4; k++) {
            int u = lane + k * 64;
            int row = u >> 3, c8 = u & 7;
            unsigned long long lo = *(const unsigned long long*)(&bb[row * 68 + c8 * 8]);
            unsigned long long hi = *(const unsigned long long*)(&bb[row * 68 + c8 * 8 + 4]);
            ulonglong2 val; val.x = lo; val.y = hi;
            *(ulonglong2*)(dst + (chunk * LTOT + mbase + wv * 32 + row) * 64 + c8 * 8) = val;
        }
        __syncthreads();
        buf ^= 1;
    }
}

// ---------- K3: fused conv+ssm, 32-token blocks -> 4 INDEPENDENT blocks/CU ----------
// Key change vs R3/R7 (64-tok, 2 blocks/CU): occupancy lever is more independent
// block-chains per CU, not wider blocks (R4/R6 disproved wider). LDS 40448 B:
//   xcb bf16[32][392] = 25088
//   region1[15360] multi-phase: {conv weights} -> {Bf/Cf f32 + bcarr} -> {dts [32][200]}
// otile/P6 deleted: P5 accumulator rows are 4 consecutive tokens -> direct f32x4 store.
__global__ __launch_bounds__(256, 4) void k3_ssm(
        const __bf16* __restrict__ xin, const __bf16* __restrict__ zsb,
        const __bf16* __restrict__ wtx, const __bf16* __restrict__ wtdt,
        const __bf16* __restrict__ wtout, const float* __restrict__ wconv,
        const float* __restrict__ bconv, const float* __restrict__ bdt,
        const float* __restrict__ dskip, const float* __restrict__ gamma,
        const float* __restrict__ beta, float* __restrict__ out) {
    __shared__ __attribute__((aligned(16))) __bf16 xcb[32 * 392];   // 25088 B
    __shared__ __attribute__((aligned(16))) char region1[15360];
    // phase overlays of region1:
    float* wcvs = (float*)region1;                 // [9*384] = 13824 B (conv phase)
    float* bcvs = (float*)(region1 + 13824);       // 1536 B
    float* Bf   = (float*)region1;                 // [32][20] f32 = 2560 B (P2 phase)
    float* Cf   = (float*)(region1 + 2560);        // 2560 B
    __bf16* dts = (__bf16*)region1;                // [32][200] = 12800 B (h-loop phase)
    float* bcarr = (float*)(region1 + 12800);      // 128 B (persists bc phase -> epilogue)

    const int tid = threadIdx.x;
    const int lane = tid & 63, wv = tid >> 6;
    const int lq = lane & 15, quad = lane >> 4;
    const int t0g = blockIdx.x * 32;

    const int te = tid >> 3, part = tid & 7;      // epilogue: 32 tokens x 8 parts x 24 ch
    const long tok = t0g + te;

    // Z-prefetch from chunk-major zsb (24 VGPR), consumed in the epilogue later.
    bf16x8 zpre[6];
#pragma unroll
    for (int h = 0; h < 2; h++)
#pragma unroll
        for (int g = 0; g < 3; g++) {
            const int chg = h * 192 + part * 24 + g * 8;
            zpre[h * 3 + g] = *(const bf16x8*)(zsb + ((long)(chg >> 6) * LTOT + tok) * 64 + (chg & 63));
        }

    // P0a: stage conv weights
    for (int u = tid; u < 9 * 384; u += 256) { int ch = u / 9, tap = u % 9; wcvs[tap * 384 + ch] = wconv[u]; }
    for (int u = tid; u < 384; u += 256) bcvs[u] = bconv[u];
    __syncthreads();

    // P0b: depthwise 3x3 conv + bias + silu, chunk-major xin -> xcb (6 units/thr)
    const int hblk = (t0g & (LL - 1)) >> 7;   // uniform per block (32 tokens within one row)
    const int w0 = t0g & 127;                 // 0/32/64/96
#pragma unroll
    for (int k = 0; k < 6; k++) {
        int u = tid + k * 256;                // 1536 units = 32 tok x 48 ch-groups
        int t = u / 48, c8 = u % 48;
        long tk = t0g + t;
        const long cbase = (long)(c8 >> 3) * LTOT;
        const int coff = (c8 & 7) * 8;
        float acc[8];
        float4 b0 = *(const float4*)(bcvs + c8 * 8);
        float4 b1 = *(const float4*)(bcvs + c8 * 8 + 4);
        acc[0] = b0.x; acc[1] = b0.y; acc[2] = b0.z; acc[3] = b0.w;
        acc[4] = b1.x; acc[5] = b1.y; acc[6] = b1.z; acc[7] = b1.w;
#pragma unroll
        for (int dy = -1; dy <= 1; dy++) {
            int h2 = hblk + dy;
            if (h2 < 0 || h2 >= HH) continue;   // block-uniform branch
#pragma unroll
            for (int dx = -1; dx <= 1; dx++) {
                int w2 = w0 + t + dx;
                if (w2 < 0 || w2 >= WW) continue;
                bf16x8 v = *(const bf16x8*)(xin + (cbase + tk + dy * WW + dx) * 64 + coff);
                const float* wp = &wcvs[((dy + 1) * 3 + (dx + 1)) * 384 + c8 * 8];
#pragma unroll
                for (int j = 0; j < 8; j++) acc[j] += (float)v[j] * wp[j];
            }
        }
        bf16x8 r;
#pragma unroll
        for (int j = 0; j < 8; j++) r[j] = (__bf16)silu_f(acc[j]);
        *(bf16x8*)(&xcb[t * 392 + c8 * 8]) = r;
    }
    __syncthreads();

    // P2: x_ssm = xc @ w_x. Wave split: wv&1 = m-tile, wv>>1 = B(0)/C(1). f32 staging.
    {
        const int wt = wv & 1, wsel = wv >> 1;
        f32x4 a4 = {0.f, 0.f, 0.f, 0.f};
#pragma unroll
        for (int ks = 0; ks < 12; ks++) {
            bf16x8 a = *(const bf16x8*)(&xcb[(wt * 16 + lq) * 392 + ks * 32 + quad * 8]);
            bf16x8 b = *(const bf16x8*)(wtx + (wsel * 16 + lq) * 384 + ks * 32 + quad * 8);
            a4 = mfma16(a, b, a4);
        }
        float* dstf = wsel ? Cf : Bf;
#pragma unroll
        for (int r = 0; r < 4; r++)
            dstf[(wt * 16 + quad * 4 + r) * 20 + lq] = a4[r];
    }
    __syncthreads();

    // bc = sum_s B*C per token (8-lane shfl tree) + aA fragments straight from f32 Bf
    {
        int t = tid >> 3;
        int s0 = (tid & 7) * 2;
        float p = Bf[t * 20 + s0] * Cf[t * 20 + s0] + Bf[t * 20 + s0 + 1] * Cf[t * 20 + s0 + 1];
        p += __shfl_xor(p, 1, 64);
        p += __shfl_xor(p, 2, 64);
        p += __shfl_xor(p, 4, 64);
        if ((lane & 7) == 0) bcarr[t] = p;
    }
    bf16x8 zero8;
#pragma unroll
    for (int j = 0; j < 8; j++) zero8[j] = (__bf16)0.f;
    bf16x8 aA[2];
#pragma unroll
    for (int mt = 0; mt < 2; mt++) {
        if (quad < 2) {
            const float* bp = Bf + (mt * 16 + lq) * 20 + quad * 8;
            f32x4 lo = *(const f32x4*)(bp);
            f32x4 hi = *(const f32x4*)(bp + 4);
            bf16x8 t8;
            t8[0] = (__bf16)lo[0]; t8[1] = (__bf16)lo[1]; t8[2] = (__bf16)lo[2]; t8[3] = (__bf16)lo[3];
            t8[4] = (__bf16)hi[0]; t8[5] = (__bf16)hi[1]; t8[6] = (__bf16)hi[2]; t8[7] = (__bf16)hi[3];
            aA[mt] = t8;
        } else {
            aA[mt] = zero8;
        }
    }
    __syncthreads();   // bcarr visible; Bf/Cf reads done before dt scatter overwrites

    float s1 = 0.f, s2 = 0.f;

#pragma unroll
    for (int h = 0; h < 2; h++) {
        // P3a: dt MFMA, 12 n-tiles / 4 waves = 3 each; 2 m-tiles.
        f32x4 dacc[3][2];
        float bdtv[3];
#pragma unroll
        for (int j = 0; j < 3; j++) {
            int chg = h * 192 + (wv * 3 + j) * 16 + lq;
            bf16x8 bf = (quad < 2) ? *(const bf16x8*)(wtdt + (long)chg * 16 + quad * 8) : zero8;
            bdtv[j] = bdt[chg];
#pragma unroll
            for (int mt = 0; mt < 2; mt++) {
                f32x4 z4 = {0.f, 0.f, 0.f, 0.f};
                dacc[j][mt] = mfma16(aA[mt], bf, z4);
            }
        }
        // scatter dt(+b_dt) to LDS (stride 200)
#pragma unroll
        for (int j = 0; j < 3; j++)
#pragma unroll
            for (int mt = 0; mt < 2; mt++)
#pragma unroll
                for (int r = 0; r < 4; r++)
                    dts[(mt * 16 + quad * 4 + r) * 200 + (wv * 3 + j) * 16 + lq] =
                        (__bf16)(dacc[j][mt][r] + bdtv[j]);
        __syncthreads();

        // epilogue: y = (softplus(dt)*bc + xc*dskip) * z ; accumulate LN stats (3 groups)
#pragma unroll
        for (int g = 0; g < 3; g++) {
            const int chl = part * 24 + g * 8;
            const int chg = h * 192 + chl;
            bf16x8 d8 = *(const bf16x8*)(&dts[te * 200 + chl]);
            bf16x8 xc8 = *(const bf16x8*)(&xcb[te * 392 + chg]);
            bf16x8 z8 = zpre[h * 3 + g];
            float4 d0 = *(const float4*)(dskip + chg);
            float4 d1 = *(const float4*)(dskip + chg + 4);
            float ds[8] = {d0.x, d0.y, d0.z, d0.w, d1.x, d1.y, d1.z, d1.w};
            const float bcv = bcarr[te];
#pragma unroll
            for (int j = 0; j < 8; j++) {
                float dtv = softplus_fast((float)d8[j]);
                float yv = (dtv * bcv + (float)xc8[j] * ds[j]) * (float)z8[j];
                s1 += yv; s2 += yv * yv;
                xc8[j] = (__bf16)yv;
            }
            *(bf16x8*)(&xcb[te * 392 + chg]) = xc8;
        }
        __syncthreads();  // dts reads done before next half's scatter
    }

    // LN (thread owns 6 channel-groups; stats reduce over 8 parts via shfl)
    {
        s1 += __shfl_xor(s1, 1, 64); s2 += __shfl_xor(s2, 1, 64);
        s1 += __shfl_xor(s1, 2, 64); s2 += __shfl_xor(s2, 2, 64);
        s1 += __shfl_xor(s1, 4, 64); s2 += __shfl_xor(s2, 4, 64);
        float mu = s1 * (1.f / 384.f);
        float var = s2 * (1.f / 384.f) - mu * mu;
        float rstd = rsqrtf(var + 1e-5f);
#pragma unroll
        for (int gg = 0; gg < 6; gg++) {
            const int h2 = gg / 3, g3 = gg % 3;
            const int ch = h2 * 192 + part * 24 + g3 * 8;
            bf16x8 v = *(const bf16x8*)(&xcb[te * 392 + ch]);
            float4 g0 = *(const float4*)(gamma + ch);
            float4 g1 = *(const float4*)(gamma + ch + 4);
            float4 be0 = *(const float4*)(beta + ch);
            float4 be1 = *(const float4*)(beta + ch + 4);
            float gm[8] = {g0.x, g0.y, g0.z, g0.w, g1.x, g1.y, g1.z, g1.w};
            float bt[8] = {be0.x, be0.y, be0.z, be0.w, be1.x, be1.y, be1.z, be1.w};
#pragma unroll
            for (int j = 0; j < 8; j++) v[j] = (__bf16)(((float)v[j] - mu) * rstd * gm[j] + bt[j]);
            *(bf16x8*)(&xcb[te * 392 + ch]) = v;
        }
    }
    __syncthreads();

    // P5: out GEMM y[32,384] @ wt_out^T -> [32,192]; DIRECT f32x4 stores to out.
    // acc[j][mt][r] holds tokens mt*16+quad*4+r (r=0..3 consecutive) for channel c.
    {
        const int bimg = t0g >> 14;
        const int l0 = t0g & (LL - 1);
        f32x4 acc[3][2];
#pragma unroll
        for (int j = 0; j < 3; j++)
#pragma unroll
            for (int mt = 0; mt < 2; mt++) acc[j][mt] = (f32x4){0.f, 0.f, 0.f, 0.f};
#pragma unroll
        for (int ks = 0; ks < 12; ks++) {
            bf16x8 bfr[3];
#pragma unroll
            for (int j = 0; j < 3; j++) {
                int c = (wv * 3 + j) * 16 + lq;
                bfr[j] = *(const bf16x8*)(wtout + (long)c * 384 + ks * 32 + quad * 8);
            }
#pragma unroll
            for (int mt = 0; mt < 2; mt++) {
                bf16x8 afr = *(const bf16x8*)(&xcb[(mt * 16 + lq) * 392 + ks * 32 + quad * 8]);
#pragma unroll
                for (int j = 0; j < 3; j++) acc[j][mt] = mfma16(afr, bfr[j], acc[j][mt]);
            }
        }
#pragma unroll
        for (int j = 0; j < 3; j++) {
            const int c = (wv * 3 + j) * 16 + lq;
#pragma unroll
            for (int mt = 0; mt < 2; mt++)
                *(f32x4*)(out + ((long)(bimg * CC + c)) * LL + l0 + mt * 16 + quad * 4) = acc[j][mt];
        }
    }
}

// ---------- launch ----------
extern "C" void kernel_launch(void* const* d_in, const int* in_sizes, int n_in,
                              void* d_out, int out_size, void* d_ws, size_t ws_size,
                              hipStream_t stream) {
    (void)in_sizes; (void)n_in; (void)out_size; (void)ws_size;
    const float* x      = (const float*)d_in[0];
    const float* w_in   = (const float*)d_in[1];
    const float* w_conv = (const float*)d_in[2];
    const float* b_conv = (const float*)d_in[3];
    const float* w_x    = (const float*)d_in[4];
    const float* w_dt   = (const float*)d_in[5];
    const float* b_dt   = (const float*)d_in[6];
    const float* D_skip = (const float*)d_in[7];
    const float* w_out  = (const float*)d_in[8];
    const float* gamma  = (const float*)d_in[9];
    const float* beta   = (const float*)d_in[10];
    float* out = (float*)d_out;

    char* ws = (char*)d_ws;
    __bf16* wt_in  = (__bf16*)(ws);                       // 294912 B (swizzled layout)
    __bf16* wt_x   = (__bf16*)(ws + 294912);              // 24576 B
    __bf16* wt_dt  = (__bf16*)(ws + 319488);              // 12288 B
    __bf16* wt_out = (__bf16*)(ws + 331776);              // 147456 B
    __bf16* xin    = (__bf16*)(ws + 479232);              // 100663296 B (chunk-major)
    __bf16* zsb    = (__bf16*)(ws + 479232 + 100663296);  // 100663296 B (chunk-major)

    k0_prep<<<96, 256, 0, stream>>>(w_in, w_x, w_dt, w_out, wt_in, wt_x, wt_dt, wt_out);
    k1_proj<<<1024, 256, 0, stream>>>(x, wt_in, xin, zsb);
    k3_ssm<<<4096, 256, 0, stream>>>(xin, zsb, wt_x, wt_dt, wt_out, w_conv, b_conv,
                                     b_dt, D_skip, gamma, beta, out);
}